// Round 4
// baseline (1919.422 us; speedup 1.0000x reference)
//
#include <hip/hip_runtime.h>

#define A3 180
#define A2 128
#define W2D 384
#define NV 192
#define NU 256
#define VZ 192
#define VY 192
#define VX 192
#define ZPT 16
#define ACHUNK 8

static constexpr double PI_D = 3.14159265358979323846;

// ---------------- Kernel T: trig tables ----------------
__global__ void tables_kernel(float* __restrict__ c2, float* __restrict__ s2,
                              float* __restrict__ cbt, float* __restrict__ sbt) {
    int i = threadIdx.x;
    if (i < A2) {
        float th = (float)i * (float)(PI_D / A2);
        c2[i] = cosf(th);
        s2[i] = sinf(th);
    }
    if (i < A3) {
        float be = (float)i * (float)(2.0 * PI_D / A3);
        cbt[i] = cosf(be);
        sbt[i] = sinf(be);
    }
}

// ---------------- Kernel A: d = grad_last(sino * weight) ----------------
__global__ __launch_bounds__(W2D) void grad_kernel(const float* __restrict__ sino,
                                                   const float* __restrict__ wini,
                                                   float* __restrict__ d) {
    __shared__ float p[W2D];
    size_t base = (size_t)blockIdx.x * W2D;
    int w = threadIdx.x;
    p[w] = sino[base + w] * wini[base + w];
    __syncthreads();
    float g;
    if (w == 0)            g = p[1] - p[0];
    else if (w == W2D - 1) g = p[W2D - 1] - p[W2D - 2];
    else                   g = (p[w + 1] - p[w - 1]) * 0.5f;
    d[base + w] = g;
}

// ---------------- Kernel B: 2D parallel BP + cosine weight ----------------
// pos provably in [32.2, 350.8]: no masks, trunc==floor. Loads pinned live
// via asm so all 16 gathers per chunk stay in flight (MLP).
__global__ __launch_bounds__(NU) void bp2d_kernel(const float* __restrict__ d,
                                                  const float* __restrict__ c2,
                                                  const float* __restrict__ s2,
                                                  float* __restrict__ wcb) {
    int u = threadIdx.x;
    int v = blockIdx.x;
    int a3 = blockIdx.y;
    float uf = (float)u - 127.5f;           // x/2
    float vf = (float)v - 95.5f;            // y/2
    unsigned slab = (unsigned)a3 * (A2 * W2D);
    float acc = 0.0f;
    for (int a0 = 0; a0 < A2; a0 += ACHUNK) {
        float r0v[ACHUNK], r1v[ACHUNK], fv[ACHUNK];
#pragma unroll
        for (int j = 0; j < ACHUNK; ++j) {
            int a = a0 + j;
            float pos = fmaf(uf, c2[a], fmaf(vf, s2[a], 191.5f));
            int i0 = (int)pos;              // pos > 0 -> trunc == floor
            fv[j] = __builtin_amdgcn_fractf(pos);
            unsigned off = slab + (unsigned)(a * W2D) + (unsigned)i0;
            r0v[j] = d[off];
            r1v[j] = d[off + 1];
        }
#pragma unroll
        for (int j = 0; j < ACHUNK; ++j)
            asm volatile("" : "+v"(r0v[j]), "+v"(r1v[j]));
#pragma unroll
        for (int j = 0; j < ACHUNK; ++j) {
            acc += fmaf(fv[j], r1v[j] - r0v[j], r0v[j]);
        }
    }
    float x = uf * 2.0f, y = vf * 2.0f;
    float w3 = 1200.0f * __builtin_amdgcn_rsqf(1440000.0f + x * x + y * y);
    float scale = (float)((PI_D / A2) * (2.0 * PI_D / A3));
    wcb[((size_t)a3 * NV + v) * NU + u] = acc * scale * w3;
}

// ---------------- Kernel C: cone-beam BP ----------------
// Per beta: issue all 64 gathers (16 z x 4 taps), pin them live with asm
// (forces materialization -> 64 loads in flight), then FMA.
__global__ __launch_bounds__(VX, 4) void conebp_kernel(const float* __restrict__ wcb,
                                                       const float* __restrict__ cbt,
                                                       const float* __restrict__ sbt,
                                                       float* __restrict__ out) {
    int x = threadIdx.x;
    int y = blockIdx.x;
    int z0 = blockIdx.y * ZPT;
    float xf = (float)x - 95.5f;
    float yf = (float)y - 95.5f;
    float z0f = (float)z0 - 95.5f;

    float acc[ZPT];
#pragma unroll
    for (int k = 0; k < ZPT; ++k) acc[k] = 0.0f;

    for (int a = 0; a < A3; ++a) {
        float cb = cbt[a], sb = sbt[a];
        float r = xf * cb + yf * sb;
        float t = yf * cb - xf * sb;
        float inv = __builtin_amdgcn_rcpf(750.0f - r);
        float iu = 600.0f * t * inv + 135.5f;   // 127.5 + 8 bias -> iu > 0
        int u0b = (int)iu;                       // trunc == floor
        float fu = iu - (float)u0b;
        int u0 = u0b - 8;
        int u0c = min(max(u0, 0), NU - 1);
        int u1c = min(max(u0 + 1, 0), NU - 1);
        float w = 750.0f * inv;
        w = w * w;                               // (DSO/denom)^2
        float wa = (u0 >= 0 && u0 < NU) ? (1.0f - fu) * w : 0.0f;
        float wb = (u0 >= -1 && u0 < NU - 1) ? fu * w : 0.0f;
        float dstep = 600.0f * inv;
        float iv0 = dstep * z0f + 95.5f;         // iv in [2.3, 188.7] always
        unsigned abase = (unsigned)a * (NV * NU);
        unsigned sl0 = abase + (unsigned)u0c;
        unsigned sl1 = abase + (unsigned)u1c;

        float p00[ZPT], p01[ZPT], p10[ZPT], p11[ZPT], fvv[ZPT];
#pragma unroll
        for (int k = 0; k < ZPT; ++k) {
            float iv = iv0 + (float)k * dstep;
            int v0 = (int)iv;                    // trunc == floor
            fvv[k] = __builtin_amdgcn_fractf(iv);
            unsigned o = ((unsigned)v0) << 8;    // v0 * NU
            p00[k] = wcb[sl0 + o];
            p01[k] = wcb[sl1 + o];
            p10[k] = wcb[sl0 + o + NU];          // v1 = v0+1: +1024B imm
            p11[k] = wcb[sl1 + o + NU];
        }
#pragma unroll
        for (int k = 0; k < ZPT; ++k)
            asm volatile("" : "+v"(p00[k]), "+v"(p01[k]), "+v"(p10[k]), "+v"(p11[k]));
#pragma unroll
        for (int k = 0; k < ZPT; ++k) {
            float r0 = fmaf(p00[k], wa, p01[k] * wb);
            float r1 = fmaf(p10[k], wa, p11[k] * wb);
            acc[k] = fmaf(fvv[k], r1 - r0, acc[k] + r0);
        }
    }
#pragma unroll
    for (int k = 0; k < ZPT; ++k) {
        out[(((size_t)(z0 + k)) * VY + y) * VX + x] = acc[k];
    }
}

extern "C" void kernel_launch(void* const* d_in, const int* in_sizes, int n_in,
                              void* d_out, int out_size, void* d_ws, size_t ws_size,
                              hipStream_t stream) {
    const float* sino = (const float*)d_in[0];  // [1,1,A3,A2,W2D] flat
    const float* wini = (const float*)d_in[1];  // [A3,A2,W2D] flat
    float* out = (float*)d_out;                 // [1,VZ,VY,VX] flat

    float* d   = (float*)d_ws;                        // A3*A2*W2D
    float* wcb = d + (size_t)A3 * A2 * W2D;           // A3*NV*NU
    float* c2  = wcb + (size_t)A3 * NV * NU;
    float* s2  = c2 + A2;
    float* cbt = s2 + A2;
    float* sbt = cbt + A3;

    tables_kernel<<<1, 256, 0, stream>>>(c2, s2, cbt, sbt);
    grad_kernel<<<A3 * A2, W2D, 0, stream>>>(sino, wini, d);
    bp2d_kernel<<<dim3(NV, A3), NU, 0, stream>>>(d, c2, s2, wcb);
    conebp_kernel<<<dim3(VY, VZ / ZPT), VX, 0, stream>>>(wcb, cbt, sbt, out);
}

// Round 5
// 1141.732 us; speedup vs baseline: 1.6812x; 1.6812x over previous
//
#include <hip/hip_runtime.h>

#define A3 180
#define A2 128
#define W2D 384
#define NV 192
#define NU 256
#define VZ 192
#define VY 192
#define VX 192
#define ACHUNK 8

// cone-BP tile geometry
#define BX 32
#define BY 8
#define CZPT 16
#define SPAN_U 64      // u window cols (proven span <= 58)
#define SPAN_V 26      // v window rows (proven span <= 22)
#define WST 66         // padded row stride in floats

static constexpr double PI_D = 3.14159265358979323846;

// ---------------- Kernel T: trig tables ----------------
__global__ void tables_kernel(float* __restrict__ c2, float* __restrict__ s2,
                              float* __restrict__ cbt, float* __restrict__ sbt) {
    int i = threadIdx.x;
    if (i < A2) {
        float th = (float)i * (float)(PI_D / A2);
        c2[i] = cosf(th);
        s2[i] = sinf(th);
    }
    if (i < A3) {
        float be = (float)i * (float)(2.0 * PI_D / A3);
        cbt[i] = cosf(be);
        sbt[i] = sinf(be);
    }
}

// ---------------- Kernel A: d = grad_last(sino * weight) ----------------
__global__ __launch_bounds__(W2D) void grad_kernel(const float* __restrict__ sino,
                                                   const float* __restrict__ wini,
                                                   float* __restrict__ d) {
    __shared__ float p[W2D];
    size_t base = (size_t)blockIdx.x * W2D;
    int w = threadIdx.x;
    p[w] = sino[base + w] * wini[base + w];
    __syncthreads();
    float g;
    if (w == 0)            g = p[1] - p[0];
    else if (w == W2D - 1) g = p[W2D - 1] - p[W2D - 2];
    else                   g = (p[w + 1] - p[w - 1]) * 0.5f;
    d[base + w] = g;
}

// ---------------- Kernel B: 2D parallel BP + cosine weight ----------------
// pos provably in [32.2, 350.8]: no masks, trunc==floor.
__global__ __launch_bounds__(NU) void bp2d_kernel(const float* __restrict__ d,
                                                  const float* __restrict__ c2,
                                                  const float* __restrict__ s2,
                                                  float* __restrict__ wcb) {
    int u = threadIdx.x;
    int v = blockIdx.x;
    int a3 = blockIdx.y;
    float uf = (float)u - 127.5f;           // x/2
    float vf = (float)v - 95.5f;            // y/2
    unsigned slab = (unsigned)a3 * (A2 * W2D);
    float acc = 0.0f;
    for (int a0 = 0; a0 < A2; a0 += ACHUNK) {
        float r0v[ACHUNK], r1v[ACHUNK], fv[ACHUNK];
#pragma unroll
        for (int j = 0; j < ACHUNK; ++j) {
            int a = a0 + j;
            float pos = fmaf(uf, c2[a], fmaf(vf, s2[a], 191.5f));
            int i0 = (int)pos;              // pos > 0 -> trunc == floor
            fv[j] = __builtin_amdgcn_fractf(pos);
            unsigned off = slab + (unsigned)(a * W2D) + (unsigned)i0;
            r0v[j] = d[off];
            r1v[j] = d[off + 1];
        }
#pragma unroll
        for (int j = 0; j < ACHUNK; ++j)
            asm volatile("" : "+v"(r0v[j]), "+v"(r1v[j]));
#pragma unroll
        for (int j = 0; j < ACHUNK; ++j) {
            acc += fmaf(fv[j], r1v[j] - r0v[j], r0v[j]);
        }
    }
    float x = uf * 2.0f, y = vf * 2.0f;
    float w3 = 1200.0f * __builtin_amdgcn_rsqf(1440000.0f + x * x + y * y);
    float scale = (float)((PI_D / A2) * (2.0 * PI_D / A3));
    wcb[((size_t)a3 * NV + v) * NU + u] = acc * scale * w3;
}

// ---------------- Kernel C: cone-beam BP, LDS-tiled ----------------
// Block = 32x * 8y tile, CZPT z per thread. Per beta: block-reduce the exact
// (umin, vmin) window origin, stage a 26x64 wcb window into LDS (coalesced,
// one wave-row per stage op), then all 4 bilinear taps come from LDS as
// ds_read2_b32 pairs. Window spans proven at compile time:
//   u-span <= 1.42*31 + 1.62*7 + 2 ~ 58 < 64;  v-span <= 14.63+4.82+2 < 26.
__global__ __launch_bounds__(256) void conebp_kernel(const float* __restrict__ wcb,
                                                     const float* __restrict__ cbt,
                                                     const float* __restrict__ sbt,
                                                     float* __restrict__ out) {
    __shared__ float win[SPAN_V * WST];
    __shared__ int redu[4], redv[4];

    int tid = threadIdx.x;
    int tx = tid & (BX - 1);
    int ty = tid >> 5;
    int wid = tid >> 6;
    int lane = tid & 63;

    int x = blockIdx.x * BX + tx;
    int y = blockIdx.y * BY + ty;
    int z0 = blockIdx.z * CZPT;

    float xf = (float)x - 95.5f;
    float yf = (float)y - 95.5f;
    float z0f = (float)z0 - 95.5f;

    float acc[CZPT];
#pragma unroll
    for (int k = 0; k < CZPT; ++k) acc[k] = 0.0f;

    for (int a = 0; a < A3; ++a) {
        float cb = cbt[a], sb = sbt[a];
        float r = xf * cb + yf * sb;
        float t = yf * cb - xf * sb;
        float inv = __builtin_amdgcn_rcpf(750.0f - r);
        float iub = fmaf(600.0f * t, inv, 135.5f);   // iu + 8, always > 0
        int u0b = (int)iub;                           // trunc == floor
        float fu = iub - (float)u0b;
        int u0 = u0b - 8;
        float wgt = 750.0f * inv;
        wgt *= wgt;                                   // (DSO/denom)^2
        float wa = ((unsigned)u0 < NU) ? (1.0f - fu) * wgt : 0.0f;
        float wb = ((unsigned)(u0 + 1) < NU) ? fu * wgt : 0.0f;
        float dstep = 600.0f * inv;
        float iv0 = fmaf(dstep, z0f, 95.5f);          // iv in [2.3,188.7]
        int vlo = (int)iv0;                           // min over k at k=0

        // exact block-min of u0 and vlo
        int um = u0, vm = vlo;
#pragma unroll
        for (int o = 32; o; o >>= 1) {
            um = min(um, __shfl_xor(um, o));
            vm = min(vm, __shfl_xor(vm, o));
        }
        if (lane == 0) { redu[wid] = um; redv[wid] = vm; }
        __syncthreads();                  // red ready; prev-beta taps done
        int umin = min(min(redu[0], redu[1]), min(redu[2], redu[3]));
        int vmin = min(min(redv[0], redv[1]), min(redv[2], redv[3]));

        // stage window: wave `wid` stages rows wid, wid+4, ... (64 lanes = 64 cols)
        const float* slab = wcb + (size_t)a * (NV * NU);
#pragma unroll
        for (int p = 0; p < 7; ++p) {
            int row = p * 4 + wid;
            if (row < SPAN_V) {           // wave-uniform predicate
                int rowg = min(vmin + row, NV - 1);
                int colg = min(max(umin + lane, 0), NU - 1);
                win[row * WST + lane] = slab[rowg * NU + colg];
            }
        }
        __syncthreads();                  // window staged

        int du = u0 - umin;               // in [0, 57]
#pragma unroll
        for (int k = 0; k < CZPT; ++k) {
            float iv = fmaf((float)k, dstep, iv0);
            int v0 = (int)iv;             // trunc == floor (iv > 0)
            float fv = iv - (float)v0;
            int idx = (v0 - vmin) * WST + du;
            float p00 = win[idx];
            float p01 = win[idx + 1];         // ds_read2_b32 pair
            float p10 = win[idx + WST];
            float p11 = win[idx + WST + 1];   // ds_read2_b32 pair
            float r0 = fmaf(p00, wa, p01 * wb);
            float r1 = fmaf(p10, wa, p11 * wb);
            acc[k] = fmaf(fv, r1 - r0, acc[k] + r0);
        }
    }

#pragma unroll
    for (int k = 0; k < CZPT; ++k) {
        out[(((size_t)(z0 + k)) * VY + y) * VX + x] = acc[k];
    }
}

extern "C" void kernel_launch(void* const* d_in, const int* in_sizes, int n_in,
                              void* d_out, int out_size, void* d_ws, size_t ws_size,
                              hipStream_t stream) {
    const float* sino = (const float*)d_in[0];  // [1,1,A3,A2,W2D] flat
    const float* wini = (const float*)d_in[1];  // [A3,A2,W2D] flat
    float* out = (float*)d_out;                 // [1,VZ,VY,VX] flat

    float* d   = (float*)d_ws;                        // A3*A2*W2D
    float* wcb = d + (size_t)A3 * A2 * W2D;           // A3*NV*NU
    float* c2  = wcb + (size_t)A3 * NV * NU;
    float* s2  = c2 + A2;
    float* cbt = s2 + A2;
    float* sbt = cbt + A3;

    tables_kernel<<<1, 256, 0, stream>>>(c2, s2, cbt, sbt);
    grad_kernel<<<A3 * A2, W2D, 0, stream>>>(sino, wini, d);
    bp2d_kernel<<<dim3(NV, A3), NU, 0, stream>>>(d, c2, s2, wcb);
    conebp_kernel<<<dim3(VX / BX, VY / BY, VZ / CZPT), 256, 0, stream>>>(wcb, cbt, sbt, out);
}

// Round 6
// 1110.412 us; speedup vs baseline: 1.7286x; 1.0282x over previous
//
#include <hip/hip_runtime.h>

#define A3 180
#define A2 128
#define W2D 384
#define NV 192
#define NU 256
#define VZ 192
#define VY 192
#define VX 192
#define ACHUNK 8

// cone-BP tile geometry
#define BX 32
#define BY 8
#define CZPT 16
#define SPAN_V 26      // v window rows (proven span <= 24 incl. margin)
#define WST 67         // padded row stride in floats (64 cols staged)

static constexpr double PI_D = 3.14159265358979323846;

// ---------------- Kernel T: trig tables ----------------
__global__ void tables_kernel(float* __restrict__ c2, float* __restrict__ s2,
                              float* __restrict__ cbt, float* __restrict__ sbt) {
    int i = threadIdx.x;
    if (i < A2) {
        float th = (float)i * (float)(PI_D / A2);
        c2[i] = cosf(th);
        s2[i] = sinf(th);
    }
    if (i < A3) {
        float be = (float)i * (float)(2.0 * PI_D / A3);
        cbt[i] = cosf(be);
        sbt[i] = sinf(be);
    }
}

// ---------------- Kernel A: d = grad_last(sino * weight) ----------------
__global__ __launch_bounds__(W2D) void grad_kernel(const float* __restrict__ sino,
                                                   const float* __restrict__ wini,
                                                   float* __restrict__ d) {
    __shared__ float p[W2D];
    size_t base = (size_t)blockIdx.x * W2D;
    int w = threadIdx.x;
    p[w] = sino[base + w] * wini[base + w];
    __syncthreads();
    float g;
    if (w == 0)            g = p[1] - p[0];
    else if (w == W2D - 1) g = p[W2D - 1] - p[W2D - 2];
    else                   g = (p[w + 1] - p[w - 1]) * 0.5f;
    d[base + w] = g;
}

// ---------------- Kernel B: 2D parallel BP + cosine weight ----------------
__global__ __launch_bounds__(NU) void bp2d_kernel(const float* __restrict__ d,
                                                  const float* __restrict__ c2,
                                                  const float* __restrict__ s2,
                                                  float* __restrict__ wcb) {
    int u = threadIdx.x;
    int v = blockIdx.x;
    int a3 = blockIdx.y;
    float uf = (float)u - 127.5f;           // x/2
    float vf = (float)v - 95.5f;            // y/2
    unsigned slab = (unsigned)a3 * (A2 * W2D);
    float acc = 0.0f;
    for (int a0 = 0; a0 < A2; a0 += ACHUNK) {
        float r0v[ACHUNK], r1v[ACHUNK], fv[ACHUNK];
#pragma unroll
        for (int j = 0; j < ACHUNK; ++j) {
            int a = a0 + j;
            float pos = fmaf(uf, c2[a], fmaf(vf, s2[a], 191.5f));
            int i0 = (int)pos;              // pos > 0 -> trunc == floor
            fv[j] = __builtin_amdgcn_fractf(pos);
            unsigned off = slab + (unsigned)(a * W2D) + (unsigned)i0;
            r0v[j] = d[off];
            r1v[j] = d[off + 1];
        }
#pragma unroll
        for (int j = 0; j < ACHUNK; ++j)
            asm volatile("" : "+v"(r0v[j]), "+v"(r1v[j]));
#pragma unroll
        for (int j = 0; j < ACHUNK; ++j) {
            acc += fmaf(fv[j], r1v[j] - r0v[j], r0v[j]);
        }
    }
    float x = uf * 2.0f, y = vf * 2.0f;
    float w3 = 1200.0f * __builtin_amdgcn_rsqf(1440000.0f + x * x + y * y);
    float scale = (float)((PI_D / A2) * (2.0 * PI_D / A3));
    wcb[((size_t)a3 * NV + v) * NU + u] = acc * scale * w3;
}

// Corner-derived window origin: iu, iv are Moebius (monotone) along tile
// edges (denom = 750-r > 0), so the tile min is at one of the 4 corners.
// Computed uniformly per block -> no cross-lane reduction, no extra barrier.
// Margin -1 absorbs corner-vs-lane fp rounding.
__device__ __forceinline__ void window_origin(float cxf0, float cxf1,
                                              float cyf0, float cyf1,
                                              float z0f, float cb, float sb,
                                              int& umin, int& vmin) {
    float iumin = 1e30f, ivmin = 1e30f;
#pragma unroll
    for (int c = 0; c < 4; ++c) {
        float cx = (c & 1) ? cxf1 : cxf0;
        float cy = (c & 2) ? cyf1 : cyf0;
        float rr = cx * cb + cy * sb;
        float inv = __builtin_amdgcn_rcpf(750.0f - rr);
        float tt = cy * cb - cx * sb;
        float iub = fmaf(600.0f * tt, inv, 135.5f);   // +8 bias, > 0
        float ivb = fmaf(600.0f * z0f, inv, 95.5f);   // > 2
        iumin = fminf(iumin, iub);
        ivmin = fminf(ivmin, ivb);
    }
    umin = (int)iumin - 9;   // floor - 8(bias) - 1(margin)
    vmin = (int)ivmin - 1;
}

// ---------------- Kernel C: cone-beam BP, LDS-tiled, double-buffered ----------------
// Block = 32x * 8y, CZPT z per thread. Window origin from corners (uniform);
// window for beta+1 prefetched to regs at loop top, written to the alternate
// LDS buffer after the z-loop. ONE barrier per beta.
__global__ __launch_bounds__(256) void conebp_kernel(const float* __restrict__ wcb,
                                                     const float* __restrict__ cbt,
                                                     const float* __restrict__ sbt,
                                                     float* __restrict__ out) {
    __shared__ float win[2][SPAN_V * WST];

    int tid = threadIdx.x;
    int tx = tid & (BX - 1);
    int ty = tid >> 5;
    int wid = tid >> 6;
    int lane = tid & 63;

    int x = blockIdx.x * BX + tx;
    int y = blockIdx.y * BY + ty;
    int z0 = blockIdx.z * CZPT;

    float xf = (float)x - 95.5f;
    float yf = (float)y - 95.5f;
    float z0f = (float)z0 - 95.5f;

    float cxf0 = (float)(blockIdx.x * BX) - 95.5f;
    float cxf1 = cxf0 + (float)(BX - 1);
    float cyf0 = (float)(blockIdx.y * BY) - 95.5f;
    float cyf1 = cyf0 + (float)(BY - 1);

    float acc[CZPT];
#pragma unroll
    for (int k = 0; k < CZPT; ++k) acc[k] = 0.0f;

    // prologue: stage window for a=0 into win[0]
    int pumin, pvmin;
    window_origin(cxf0, cxf1, cyf0, cyf1, z0f, cbt[0], sbt[0], pumin, pvmin);
#pragma unroll
    for (int p = 0; p < 7; ++p) {
        int row = p * 4 + wid;
        if (row < SPAN_V) {
            int rowg = min(pvmin + row, NV - 1);
            int colg = min(max(pumin + lane, 0), NU - 1);
            win[0][row * WST + lane] = wcb[rowg * NU + colg];
        }
    }
    __syncthreads();

    for (int a = 0; a < A3; ++a) {
        int cur = a & 1;

        // prefetch next beta's window into regs (issued before compute)
        int numin = 0, nvmin = 0;
        float pf[7];
        if (a + 1 < A3) {
            window_origin(cxf0, cxf1, cyf0, cyf1, z0f, cbt[a + 1], sbt[a + 1],
                          numin, nvmin);
            const float* slab = wcb + (size_t)(a + 1) * (NV * NU);
#pragma unroll
            for (int p = 0; p < 7; ++p) {
                int row = p * 4 + wid;
                if (row < SPAN_V) {
                    int rowg = min(nvmin + row, NV - 1);
                    int colg = min(max(numin + lane, 0), NU - 1);
                    pf[p] = slab[rowg * NU + colg];
                }
            }
        }

        // per-lane geometry for current beta
        float cb = cbt[a], sb = sbt[a];
        float r = xf * cb + yf * sb;
        float t = yf * cb - xf * sb;
        float inv = __builtin_amdgcn_rcpf(750.0f - r);
        float iub = fmaf(600.0f * t, inv, 135.5f);   // +8 bias, > 0
        int u0b = (int)iub;                           // trunc == floor
        float fu = iub - (float)u0b;
        int u0 = u0b - 8;
        float wgt = 750.0f * inv;
        wgt *= wgt;                                   // (DSO/denom)^2
        float wa = ((unsigned)u0 < NU) ? (1.0f - fu) * wgt : 0.0f;
        float wb = ((unsigned)(u0 + 1) < NU) ? fu * wgt : 0.0f;
        float dstep = 600.0f * inv;
        float ivr = fmaf(dstep, z0f, 95.5f - (float)pvmin);  // window-relative
        int du = u0 - pumin;                          // in [0, 62]

        const float* w0 = win[cur];
#pragma unroll
        for (int k = 0; k < CZPT; ++k) {
            float iv = fmaf((float)k, dstep, ivr);
            int v0 = (int)iv;                         // trunc == floor (iv>0)
            float fv = iv - (float)v0;
            int idx = v0 * WST + du;
            float p00 = w0[idx];
            float p01 = w0[idx + 1];
            float p10 = w0[idx + WST];
            float p11 = w0[idx + WST + 1];
            float r0 = fmaf(p00, wa, p01 * wb);
            float r1 = fmaf(p10, wa, p11 * wb);
            acc[k] = fmaf(fv, r1 - r0, acc[k] + r0);
        }

        // write prefetched window to the alternate buffer
        if (a + 1 < A3) {
#pragma unroll
            for (int p = 0; p < 7; ++p) {
                int row = p * 4 + wid;
                if (row < SPAN_V) win[cur ^ 1][row * WST + lane] = pf[p];
            }
            pumin = numin;
            pvmin = nvmin;
        }
        __syncthreads();   // one barrier per beta
    }

#pragma unroll
    for (int k = 0; k < CZPT; ++k) {
        out[(((size_t)(z0 + k)) * VY + y) * VX + x] = acc[k];
    }
}

extern "C" void kernel_launch(void* const* d_in, const int* in_sizes, int n_in,
                              void* d_out, int out_size, void* d_ws, size_t ws_size,
                              hipStream_t stream) {
    const float* sino = (const float*)d_in[0];  // [1,1,A3,A2,W2D] flat
    const float* wini = (const float*)d_in[1];  // [A3,A2,W2D] flat
    float* out = (float*)d_out;                 // [1,VZ,VY,VX] flat

    float* d   = (float*)d_ws;                        // A3*A2*W2D
    float* wcb = d + (size_t)A3 * A2 * W2D;           // A3*NV*NU
    float* c2  = wcb + (size_t)A3 * NV * NU;
    float* s2  = c2 + A2;
    float* cbt = s2 + A2;
    float* sbt = cbt + A3;

    tables_kernel<<<1, 256, 0, stream>>>(c2, s2, cbt, sbt);
    grad_kernel<<<A3 * A2, W2D, 0, stream>>>(sino, wini, d);
    bp2d_kernel<<<dim3(NV, A3), NU, 0, stream>>>(d, c2, s2, wcb);
    conebp_kernel<<<dim3(VX / BX, VY / BY, VZ / CZPT), 256, 0, stream>>>(wcb, cbt, sbt, out);
}

// Round 7
// 975.619 us; speedup vs baseline: 1.9674x; 1.1382x over previous
//
#include <hip/hip_runtime.h>

#define A3 180
#define A2 128
#define W2D 384
#define NV 192
#define NU 256
#define VZ 192
#define VY 192
#define VX 192
#define ACHUNK 8

// cone-BP tile geometry
#define BX 32
#define BY 8
#define CZPT 16
#define SPAN_V 26      // v window rows (proven span <= 24 incl. margins)
#define WST 67         // padded row stride in floats (64 cols staged)

static constexpr double PI_D = 3.14159265358979323846;

// async global->LDS, 4B per lane; LDS dest = uniform base + lane*4
#define GLOAD_LDS(gaddr, laddr)                                                  \
    __builtin_amdgcn_global_load_lds(                                            \
        (const __attribute__((address_space(1))) unsigned int*)(gaddr),          \
        (__attribute__((address_space(3))) unsigned int*)(laddr), 4, 0, 0)

// ---------------- Kernel T: trig tables ----------------
__global__ void tables_kernel(float* __restrict__ c2, float* __restrict__ s2,
                              float* __restrict__ cbt, float* __restrict__ sbt) {
    int i = threadIdx.x;
    if (i < A2) {
        float th = (float)i * (float)(PI_D / A2);
        c2[i] = cosf(th);
        s2[i] = sinf(th);
    }
    if (i < A3) {
        float be = (float)i * (float)(2.0 * PI_D / A3);
        cbt[i] = cosf(be);
        sbt[i] = sinf(be);
    }
}

// ---------------- Kernel A: d = grad_last(sino * weight) ----------------
__global__ __launch_bounds__(W2D) void grad_kernel(const float* __restrict__ sino,
                                                   const float* __restrict__ wini,
                                                   float* __restrict__ d) {
    __shared__ float p[W2D];
    size_t base = (size_t)blockIdx.x * W2D;
    int w = threadIdx.x;
    p[w] = sino[base + w] * wini[base + w];
    __syncthreads();
    float g;
    if (w == 0)            g = p[1] - p[0];
    else if (w == W2D - 1) g = p[W2D - 1] - p[W2D - 2];
    else                   g = (p[w + 1] - p[w - 1]) * 0.5f;
    d[base + w] = g;
}

// ---------------- Kernel B: 2D parallel BP + cosine weight ----------------
__global__ __launch_bounds__(NU) void bp2d_kernel(const float* __restrict__ d,
                                                  const float* __restrict__ c2,
                                                  const float* __restrict__ s2,
                                                  float* __restrict__ wcb) {
    int u = threadIdx.x;
    int v = blockIdx.x;
    int a3 = blockIdx.y;
    float uf = (float)u - 127.5f;           // x/2
    float vf = (float)v - 95.5f;            // y/2
    unsigned slab = (unsigned)a3 * (A2 * W2D);
    float acc = 0.0f;
    for (int a0 = 0; a0 < A2; a0 += ACHUNK) {
        float r0v[ACHUNK], r1v[ACHUNK], fv[ACHUNK];
#pragma unroll
        for (int j = 0; j < ACHUNK; ++j) {
            int a = a0 + j;
            float pos = fmaf(uf, c2[a], fmaf(vf, s2[a], 191.5f));
            int i0 = (int)pos;              // pos > 0 -> trunc == floor
            fv[j] = __builtin_amdgcn_fractf(pos);
            unsigned off = slab + (unsigned)(a * W2D) + (unsigned)i0;
            r0v[j] = d[off];
            r1v[j] = d[off + 1];
        }
#pragma unroll
        for (int j = 0; j < ACHUNK; ++j)
            asm volatile("" : "+v"(r0v[j]), "+v"(r1v[j]));
#pragma unroll
        for (int j = 0; j < ACHUNK; ++j) {
            acc += fmaf(fv[j], r1v[j] - r0v[j], r0v[j]);
        }
    }
    float x = uf * 2.0f, y = vf * 2.0f;
    float w3 = 1200.0f * __builtin_amdgcn_rsqf(1440000.0f + x * x + y * y);
    float scale = (float)((PI_D / A2) * (2.0 * PI_D / A3));
    wcb[((size_t)a3 * NV + v) * NU + u] = acc * scale * w3;
}

// ---------------- Kernel C: cone-beam BP ----------------
// Block = 32x * 8y, CZPT z per thread. All 180 per-block window origins
// precomputed once into LDS (corner-min; iu/iv Moebius -> monotone -> corner-
// attained). Per beta: issue next window via global_load_lds (async, zero
// VGPR), compute current from LDS, ONE barrier. VGPR pinned <=64 for full
// occupancy (launch_bounds 256,8).
__global__ __launch_bounds__(256, 8) void conebp_kernel(const float* __restrict__ wcb,
                                                        const float* __restrict__ cbt,
                                                        const float* __restrict__ sbt,
                                                        float* __restrict__ out) {
    __shared__ float win[2][SPAN_V * WST];
    __shared__ int orgs_s[A3];

    int tid = threadIdx.x;
    int tx = tid & (BX - 1);
    int ty = tid >> 5;
    int wid = tid >> 6;
    int lane = tid & 63;

    int x = blockIdx.x * BX + tx;
    int y = blockIdx.y * BY + ty;
    int z0 = blockIdx.z * CZPT;

    float xf = (float)x - 95.5f;
    float yf = (float)y - 95.5f;
    float z0f = (float)z0 - 95.5f;

    // ---- one-time: per-beta window origins from block corners ----
    {
        float cxf0 = (float)(blockIdx.x * BX) - 95.5f;
        float cxf1 = cxf0 + (float)(BX - 1);
        float cyf0 = (float)(blockIdx.y * BY) - 95.5f;
        float cyf1 = cyf0 + (float)(BY - 1);
        if (tid < A3) {
            float cbb = cbt[tid], sbb = sbt[tid];
            float iumin = 1e30f, ivmin = 1e30f;
#pragma unroll
            for (int c = 0; c < 4; ++c) {
                float cx = (c & 1) ? cxf1 : cxf0;
                float cy = (c & 2) ? cyf1 : cyf0;
                float rr = cx * cbb + cy * sbb;
                float inv = __builtin_amdgcn_rcpf(750.0f - rr);
                float tt = cy * cbb - cx * sbb;
                iumin = fminf(iumin, fmaf(600.0f * tt, inv, 135.5f));
                ivmin = fminf(ivmin, fmaf(600.0f * z0f, inv, 95.5f));
            }
            int um = (int)iumin - 9;   // floor - 8(bias) - 1(margin)
            int vm = (int)ivmin - 1;   // >= 1
            orgs_s[tid] = (vm << 16) | (um & 0xffff);
        }
    }
    __syncthreads();

    float acc[CZPT];
#pragma unroll
    for (int k = 0; k < CZPT; ++k) acc[k] = 0.0f;

    // ---- prologue: stage window for a=0 into win[0] ----
    int orgc = orgs_s[0];
    int orgn = orgs_s[1];
    {
        int umin = (int)(short)(orgc & 0xffff);
        int vmin = orgc >> 16;
#pragma unroll
        for (int p = 0; p < 7; ++p) {
            int row = p * 4 + wid;
            if (row < SPAN_V) {
                int rowg = min(vmin + row, NV - 1);
                int colg = min(max(umin + lane, 0), NU - 1);
                GLOAD_LDS(wcb + rowg * NU + colg, &win[0][row * WST]);
            }
        }
    }
    __syncthreads();

    for (int a = 0; a < A3; ++a) {
        int cur = a & 1;

        // issue next beta's window loads (async into alternate buffer)
        if (a + 1 < A3) {
            int umin = (int)(short)(orgn & 0xffff);
            int vmin = orgn >> 16;
            const float* slab = wcb + (size_t)(a + 1) * (NV * NU);
#pragma unroll
            for (int p = 0; p < 7; ++p) {
                int row = p * 4 + wid;
                if (row < SPAN_V) {
                    int rowg = min(vmin + row, NV - 1);
                    int colg = min(max(umin + lane, 0), NU - 1);
                    GLOAD_LDS(slab + rowg * NU + colg, &win[cur ^ 1][row * WST]);
                }
            }
        }

        // per-lane geometry for current beta
        float cb = cbt[a], sb = sbt[a];
        float r = xf * cb + yf * sb;
        float t = yf * cb - xf * sb;
        float inv = __builtin_amdgcn_rcpf(750.0f - r);
        float iub = fmaf(600.0f * t, inv, 135.5f);   // +8 bias, > 0
        int u0b = (int)iub;                           // trunc == floor
        float fu = iub - (float)u0b;
        int u0 = u0b - 8;
        float wgt = 750.0f * inv;
        wgt *= wgt;                                   // (DSO/denom)^2
        float wa = ((unsigned)u0 < NU) ? (1.0f - fu) * wgt : 0.0f;
        float wb = ((unsigned)(u0 + 1) < NU) ? fu * wgt : 0.0f;
        float dstep = 600.0f * inv;

        int umin_c = (int)(short)(orgc & 0xffff);
        int vmin_c = orgc >> 16;
        float ivr = fmaf(dstep, z0f, 95.5f - (float)vmin_c);  // window-rel, > 0
        const float* w0 = &win[cur][u0 - umin_c];             // du in [0,62]

#pragma unroll
        for (int k = 0; k < CZPT; ++k) {
            float iv = fmaf((float)k, dstep, ivr);
            int v0 = (int)iv;                         // trunc == floor
            float fv = iv - (float)v0;
            int idx = v0 * WST;
            float p00 = w0[idx];
            float p01 = w0[idx + 1];
            float p10 = w0[idx + WST];
            float p11 = w0[idx + WST + 1];
            float r0 = fmaf(p00, wa, p01 * wb);
            float r1 = fmaf(p10, wa, p11 * wb);
            acc[k] = fmaf(fv, r1 - r0, acc[k] + r0);
        }

        __syncthreads();   // drains global_load_lds (vmcnt) + swap
        orgc = orgn;
        orgn = orgs_s[(a + 2 < A3) ? a + 2 : 0];
    }

#pragma unroll
    for (int k = 0; k < CZPT; ++k) {
        out[(((size_t)(z0 + k)) * VY + y) * VX + x] = acc[k];
    }
}

extern "C" void kernel_launch(void* const* d_in, const int* in_sizes, int n_in,
                              void* d_out, int out_size, void* d_ws, size_t ws_size,
                              hipStream_t stream) {
    const float* sino = (const float*)d_in[0];  // [1,1,A3,A2,W2D] flat
    const float* wini = (const float*)d_in[1];  // [A3,A2,W2D] flat
    float* out = (float*)d_out;                 // [1,VZ,VY,VX] flat

    float* d   = (float*)d_ws;                        // A3*A2*W2D
    float* wcb = d + (size_t)A3 * A2 * W2D;           // A3*NV*NU
    float* c2  = wcb + (size_t)A3 * NV * NU;
    float* s2  = c2 + A2;
    float* cbt = s2 + A2;
    float* sbt = cbt + A3;

    tables_kernel<<<1, 256, 0, stream>>>(c2, s2, cbt, sbt);
    grad_kernel<<<A3 * A2, W2D, 0, stream>>>(sino, wini, d);
    bp2d_kernel<<<dim3(NV, A3), NU, 0, stream>>>(d, c2, s2, wcb);
    conebp_kernel<<<dim3(VX / BX, VY / BY, VZ / CZPT), 256, 0, stream>>>(wcb, cbt, sbt, out);
}

// Round 9
// 769.556 us; speedup vs baseline: 2.4942x; 1.2678x over previous
//
#include <hip/hip_runtime.h>

#define A3 180
#define A2 128
#define W2D 384
#define NV 192
#define NU 256
#define VZ 192
#define VY 192
#define VX 192

// cone-BP tile geometry
#define BX 32
#define BY 8
#define CZPT 16
#define WROWS 32       // v window rows (span <= 23 incl. margins)
#define WDW 64         // u window cols (live span <= 62 incl. margins+align)

// bp2d tile geometry: 32u x 32v -> per-angle pos span = 31(|c|+|s|) <= 44
#define BU2 32
#define BV2 32
#define VPT2 4
#define PW 64          // staged cols per angle (max rel tap 47 < 64)

static constexpr double PI_D = 3.14159265358979323846;

// async global->LDS; dest = wave-uniform base + lane*size
#define GLOAD16(gaddr, laddr)                                                    \
    __builtin_amdgcn_global_load_lds(                                            \
        (const __attribute__((address_space(1))) unsigned int*)(gaddr),          \
        (__attribute__((address_space(3))) unsigned int*)(laddr), 16, 0, 0)
#define GLOAD4(gaddr, laddr)                                                     \
    __builtin_amdgcn_global_load_lds(                                            \
        (const __attribute__((address_space(1))) unsigned int*)(gaddr),          \
        (__attribute__((address_space(3))) unsigned int*)(laddr), 4, 0, 0)

// ---------------- Kernel T: trig tables ----------------
__global__ void tables_kernel(float* __restrict__ c2, float* __restrict__ s2,
                              float* __restrict__ cbt, float* __restrict__ sbt) {
    int i = threadIdx.x;
    if (i < A2) {
        float th = (float)i * (float)(PI_D / A2);
        c2[i] = cosf(th);
        s2[i] = sinf(th);
    }
    if (i < A3) {
        float be = (float)i * (float)(2.0 * PI_D / A3);
        cbt[i] = cosf(be);
        sbt[i] = sinf(be);
    }
}

// ---------------- Kernel A: d = grad_last(sino * weight) ----------------
__global__ __launch_bounds__(W2D) void grad_kernel(const float* __restrict__ sino,
                                                   const float* __restrict__ wini,
                                                   float* __restrict__ d) {
    __shared__ float p[W2D];
    size_t base = (size_t)blockIdx.x * W2D;
    int w = threadIdx.x;
    p[w] = sino[base + w] * wini[base + w];
    __syncthreads();
    float g;
    if (w == 0)            g = p[1] - p[0];
    else if (w == W2D - 1) g = p[W2D - 1] - p[W2D - 2];
    else                   g = (p[w + 1] - p[w - 1]) * 0.5f;
    d[base + w] = g;
}

// ---------------- Kernel B: 2D parallel BP + cosine weight (LDS window) ----
// Tile 32u x 32v. pos = uf*c + vf*s + 191.5 is LINEAR in (u,v) -> tile min is
// exactly at a corner (separable min). Tile span = 31(|c|+|s|) <= 31*sqrt(2)
// ~ 43.9; umin margin 2 + tap +1 -> max relative index 47 < PW=64. Global
// pos in [32.1, 350.9] -> abs taps <= 351 < 384; staged-col clamp at 383
// only pads the never-read tail. 4 waves stage 4 angles/group, double-buffered.
__global__ __launch_bounds__(256) void bp2d_kernel(const float* __restrict__ d,
                                                   const float* __restrict__ c2,
                                                   const float* __restrict__ s2,
                                                   float* __restrict__ wcb) {
    __shared__ float rowwin[2][4][PW];
    __shared__ float csl[A2], ssl[A2];
    __shared__ int umin_s[A2];

    int tid = threadIdx.x;
    int ul = tid & 31;         // u within tile
    int vth = tid >> 5;        // 0..7, each handles VPT2 v's
    int wv = tid >> 6;         // wave id (staging)
    int lane = tid & 63;
    int u0g = blockIdx.x * BU2;
    int v0g = blockIdx.y * BV2;
    int a3 = blockIdx.z;

    float uf = (float)(u0g + ul) - 127.5f;
    float vf0 = (float)(v0g + vth * VPT2) - 95.5f;
    const float* slab = d + (size_t)a3 * (A2 * W2D);

    if (tid < A2) {
        float c = c2[tid], s = s2[tid];
        csl[tid] = c; ssl[tid] = s;
        float cu0 = ((float)u0g - 127.5f) * c;
        float cu1 = ((float)(u0g + BU2 - 1) - 127.5f) * c;
        float cv0 = ((float)v0g - 95.5f) * s;
        float cv1 = ((float)(v0g + BV2 - 1) - 95.5f) * s;
        float m = fminf(cu0, cu1) + fminf(cv0, cv1) + 191.5f;
        umin_s[tid] = (int)m - 2;   // >= 30; margin 2 covers fma reordering
    }
    __syncthreads();

    // prologue: stage group 0 (wave wv -> angle wv)
    {
        int um = umin_s[wv];
        int colg = min(um + lane, W2D - 1);
        GLOAD4(slab + wv * W2D + colg, &rowwin[0][wv][0]);
    }
    __syncthreads();

    float acc[VPT2];
#pragma unroll
    for (int k = 0; k < VPT2; ++k) acc[k] = 0.0f;

    for (int g = 0; g < A2 / 4; ++g) {
        int buf = g & 1;
        if (g + 1 < A2 / 4) {
            int aa = (g + 1) * 4 + wv;
            int um = umin_s[aa];
            int colg = min(um + lane, W2D - 1);
            GLOAD4(slab + aa * W2D + colg, &rowwin[buf ^ 1][wv][0]);
        }
#pragma unroll
        for (int j = 0; j < 4; ++j) {
            int aa = g * 4 + j;
            float c = csl[aa], s = ssl[aa];
            float pb = fmaf(uf, c, fmaf(vf0, s, 191.5f - (float)umin_s[aa]));
            const float* rw = rowwin[buf][j];
#pragma unroll
            for (int k = 0; k < VPT2; ++k) {
                float pos = fmaf((float)k, s, pb);   // rel pos in [~2, 47]
                int i0 = (int)pos;                   // trunc == floor (pos>0)
                float f = __builtin_amdgcn_fractf(pos);
                float r0 = rw[i0], r1 = rw[i0 + 1];
                acc[k] = fmaf(f, r1 - r0, acc[k] + r0);
            }
        }
        __syncthreads();   // drains staging; protects buffer reuse
    }

    float x = uf * 2.0f;
    float scale = (float)((PI_D / A2) * (2.0 * PI_D / A3));
#pragma unroll
    for (int k = 0; k < VPT2; ++k) {
        float y = (vf0 + (float)k) * 2.0f;
        float w3 = 1200.0f * __builtin_amdgcn_rsqf(1440000.0f + x * x + y * y);
        int v = v0g + vth * VPT2 + k;
        wcb[((size_t)a3 * NV + v) * NU + u0g + ul] = acc[k] * scale * w3;
    }
}

// ---------------- Kernel C: cone-beam BP ----------------
// Origin clamped to umin in [0,192]&~3 (16B aligned), vmin in [1,160]:
// 64x32 window ALWAYS fully inside wcb -> no per-element clamps, staging is
// 2 width-16 global_load_lds per wave per beta. Live taps proven in-window
// (u-span <= 45 + margins + align <= 62; v-span <= 23 <= 30). OOB-u taps are
// weight-masked and read finite LDS (wcb data / packed-int denormals).
__global__ __launch_bounds__(256, 8) void conebp_kernel(const float* __restrict__ wcb,
                                                        const float* __restrict__ cbt,
                                                        const float* __restrict__ sbt,
                                                        float* __restrict__ out) {
    __shared__ float win[2][WROWS * WDW];   // 16 KB
    __shared__ int orgs_s[A3 + 2];

    int tid = threadIdx.x;
    int tx = tid & (BX - 1);
    int ty = tid >> 5;
    int wid = tid >> 6;
    int lane = tid & 63;

    int x = blockIdx.x * BX + tx;
    int y = blockIdx.y * BY + ty;
    int z0 = blockIdx.z * CZPT;

    float xf = (float)x - 95.5f;
    float yf = (float)y - 95.5f;
    float z0f = (float)z0 - 95.5f;

    // ---- one-time: per-beta window origins from block corners ----
    {
        float cxf0 = (float)(blockIdx.x * BX) - 95.5f;
        float cxf1 = cxf0 + (float)(BX - 1);
        float cyf0 = (float)(blockIdx.y * BY) - 95.5f;
        float cyf1 = cyf0 + (float)(BY - 1);
        if (tid < A3) {
            float cbb = cbt[tid], sbb = sbt[tid];
            float iumin = 1e30f, ivmin = 1e30f;
#pragma unroll
            for (int c = 0; c < 4; ++c) {
                float cx = (c & 1) ? cxf1 : cxf0;
                float cy = (c & 2) ? cyf1 : cyf0;
                float rr = cx * cbb + cy * sbb;
                float inv = __builtin_amdgcn_rcpf(750.0f - rr);
                float tt = cy * cbb - cx * sbb;
                iumin = fminf(iumin, fmaf(600.0f * tt, inv, 135.5f));
                ivmin = fminf(ivmin, fmaf(600.0f * z0f, inv, 95.5f));
            }
            int um = (int)iumin - 9;              // floor -8 bias -1 margin
            um = min(max(um, 0), 192) & ~3;       // 16B-aligned, in-bounds
            int vm = min(max((int)ivmin - 1, 1), 160);
            orgs_s[tid] = (vm << 16) | um;
        }
        if (tid >= A3 && tid < A3 + 2) orgs_s[tid] = (1 << 16);
    }
    __syncthreads();

    float acc[CZPT];
#pragma unroll
    for (int k = 0; k < CZPT; ++k) acc[k] = 0.0f;

    // per-lane staging offset (dwords) in GLOBAL window layout:
    // row = wid*4 + (lane>>4), col = 4*(lane&15); global row stride 256.
    unsigned pre = ((unsigned)(lane >> 4) << 8) + ((unsigned)(lane & 15) << 2)
                 + ((unsigned)wid << 10);
    float* const win0 = &win[0][0];
    float* const win1 = &win[1][0];

    int orgc = orgs_s[0];
    int orgn = orgs_s[1];
    {   // prologue: stage beta 0 into win[0]
        unsigned umin = orgc & 0xffffu, vmin = (unsigned)orgc >> 16;
        const float* src = wcb + (vmin << 8) + umin + pre;
        float* dst = win0 + ((unsigned)wid << 8);
        GLOAD16(src, dst);
        GLOAD16(src + 4096, dst + 1024);
    }
    __syncthreads();

    for (int a = 0; a < A3; ++a) {
        int cur = a & 1;

        if (a + 1 < A3) {   // stage next beta into alternate buffer (async)
            unsigned umin = orgn & 0xffffu, vmin = (unsigned)orgn >> 16;
            const float* src = wcb + (size_t)(a + 1) * (NV * NU)
                             + (vmin << 8) + umin + pre;
            float* dst = (cur ? win0 : win1) + ((unsigned)wid << 8);
            GLOAD16(src, dst);
            GLOAD16(src + 4096, dst + 1024);
        }

        float cb = cbt[a], sb = sbt[a];
        float r = fmaf(xf, cb, yf * sb);
        float t = fmaf(yf, cb, -xf * sb);
        float inv = __builtin_amdgcn_rcpf(750.0f - r);
        float iub = fmaf(600.0f * t, inv, 135.5f);   // +8 bias, > 0
        int u0 = (int)iub - 8;
        float fu = __builtin_amdgcn_fractf(iub);
        float wgt = 750.0f * inv;
        wgt *= wgt;                                   // (DSO/denom)^2
        float wa = ((unsigned)u0 < NU) ? (1.0f - fu) * wgt : 0.0f;
        float wb = ((unsigned)(u0 + 1) < NU) ? fu * wgt : 0.0f;
        float dstep = 600.0f * inv;

        unsigned uminc = orgc & 0xffffu, vminc = (unsigned)orgc >> 16;
        float ivr = fmaf(dstep, z0f, 95.5f - (float)vminc);   // window-rel >= 1
        const float* w0 = (cur ? win1 : win0) + (u0 - (int)uminc);

#pragma unroll
        for (int k = 0; k < CZPT; ++k) {
            float iv = fmaf((float)k, dstep, ivr);
            int v0 = (int)iv;                         // trunc == floor
            float fv = __builtin_amdgcn_fractf(iv);
            int o = v0 << 6;                          // window stride 64
            float p00 = w0[o], p01 = w0[o + 1];
            float p10 = w0[o + WDW], p11 = w0[o + WDW + 1];
            float q0 = fmaf(fv, p10 - p00, p00);
            float q1 = fmaf(fv, p11 - p01, p01);
            acc[k] = fmaf(wa, q0, acc[k]);
            acc[k] = fmaf(wb, q1, acc[k]);
        }

        __syncthreads();   // drains async staging + protects buffer swap
        orgc = orgn;
        orgn = orgs_s[a + 2];
    }

#pragma unroll
    for (int k = 0; k < CZPT; ++k) {
        out[(((size_t)(z0 + k)) * VY + y) * VX + x] = acc[k];
    }
}

extern "C" void kernel_launch(void* const* d_in, const int* in_sizes, int n_in,
                              void* d_out, int out_size, void* d_ws, size_t ws_size,
                              hipStream_t stream) {
    const float* sino = (const float*)d_in[0];  // [1,1,A3,A2,W2D] flat
    const float* wini = (const float*)d_in[1];  // [A3,A2,W2D] flat
    float* out = (float*)d_out;                 // [1,VZ,VY,VX] flat

    float* d   = (float*)d_ws;                        // A3*A2*W2D
    float* wcb = d + (size_t)A3 * A2 * W2D;           // A3*NV*NU
    float* c2  = wcb + (size_t)A3 * NV * NU;
    float* s2  = c2 + A2;
    float* cbt = s2 + A2;
    float* sbt = cbt + A3;

    tables_kernel<<<1, 256, 0, stream>>>(c2, s2, cbt, sbt);
    grad_kernel<<<A3 * A2, W2D, 0, stream>>>(sino, wini, d);
    bp2d_kernel<<<dim3(NU / BU2, NV / BV2, A3), 256, 0, stream>>>(d, c2, s2, wcb);
    conebp_kernel<<<dim3(VX / BX, VY / BY, VZ / CZPT), 256, 0, stream>>>(wcb, cbt, sbt, out);
}